// Round 1
// baseline (1310.889 us; speedup 1.0000x reference)
//
#include <hip/hip_runtime.h>
#include <math.h>

// Problem constants
#define B_ 2
#define S_ 2048
#define H_ 32
#define KV_ 8
#define D_ 128
#define T_ 4096
#define HID_ 4096
#define OQKV_ 6144

typedef __attribute__((ext_vector_type(4))) float f32x4;
typedef __attribute__((ext_vector_type(8))) __bf16 bf16x8;
typedef __attribute__((ext_vector_type(4))) unsigned short u16x4;
typedef __attribute__((ext_vector_type(8))) unsigned short u16x8;
typedef unsigned short u16;

// float -> bf16 bits, RTNE (finite inputs only)
__device__ __forceinline__ u16 f2b(float f) {
  unsigned x = __float_as_uint(f);
  return (u16)((x + 0x7FFFu + ((x >> 16) & 1u)) >> 16);
}
__device__ __forceinline__ float b2f(u16 u) {
  return __uint_as_float(((unsigned)u) << 16);
}

__device__ __forceinline__ void async16(const void* g, void* l) {
  __builtin_amdgcn_global_load_lds((__attribute__((address_space(1))) void*)g,
                                   (__attribute__((address_space(3))) void*)l,
                                   16, 0, 0);
}

__device__ __forceinline__ bf16x8 ld8(const u16* p) { return *(const bf16x8*)p; }

__device__ __forceinline__ f32x4 mfma16x16(bf16x8 a, bf16x8 b, f32x4 c) {
  return __builtin_amdgcn_mfma_f32_16x16x32_bf16(a, b, c, 0, 0, 0);
}

// ---------------- elementwise kernels ----------------

// q_hidden int32 (-127..127) -> bf16 (exact). 4 elems/thread.
__global__ __launch_bounds__(256) void convert_x(const int* __restrict__ w,
                                                 u16* __restrict__ out) {
  size_t base = ((size_t)blockIdx.x * 256 + threadIdx.x) * 4;
  int4 v = *(const int4*)(w + base);
  u16x4 o = {f2b((float)v.x), f2b((float)v.y), f2b((float)v.z), f2b((float)v.w)};
  *(u16x4*)(out + base) = o;
}

// int4-range weights * per-(row,group) scale -> bf16, row-major [row][4096]
__global__ __launch_bounds__(256) void dequant_w(const int* __restrict__ w,
                                                 const float* __restrict__ s,
                                                 u16* __restrict__ out) {
  size_t base = ((size_t)blockIdx.x * 256 + threadIdx.x) * 4;
  int row = (int)(base >> 12);
  int col = (int)(base & 4095);
  float sc = s[row * 32 + (col >> 7)];
  int4 v = *(const int4*)(w + base);
  u16x4 o = {f2b(v.x * sc), f2b(v.y * sc), f2b(v.z * sc), f2b(v.w * sc)};
  *(u16x4*)(out + base) = o;
}

// NeoX RoPE in-place on bf16 qkv[t][6144]: q heads 0..31, k heads 32..39
__global__ __launch_bounds__(256) void rope_kernel(u16* __restrict__ qkv) {
  int idx = blockIdx.x * 256 + threadIdx.x;   // T * 40 * 64 total
  int t = idx / 2560;
  int r = idx - t * 2560;
  int head = r >> 6;
  int d = r & 63;
  int col = (head < 32) ? (head * 128 + d) : (4096 + (head - 32) * 128 + d);
  size_t base = (size_t)t * 6144 + col;
  float x1 = b2f(qkv[base]);
  float x2 = b2f(qkv[base + 64]);
  float e = (float)d * 0.015625f;            // d/64 exact
  float freq = 1.0f / powf(1.0e6f, e);
  float ang = (float)(t & 2047) * freq;      // pos = t mod S
  float sn, cs;
  sincosf(ang, &sn, &cs);
  qkv[base] = f2b(x1 * cs - x2 * sn);
  qkv[base + 64] = f2b(x2 * cs + x1 * sn);
}

// V slice of qkv -> VT[b][kv][d][s] (bf16). Scattered 2B reads, 16B coalesced writes.
__global__ __launch_bounds__(256) void vt_transpose(const u16* __restrict__ qkv,
                                                    u16* __restrict__ vt) {
  int gi = blockIdx.x * 256 + threadIdx.x;   // 524288 total
  int bk = gi >> 15;                         // b*8+kv
  int rem = gi & 32767;
  int d = rem >> 8;
  int s0 = (rem & 255) * 8;
  int b = bk >> 3, kv = bk & 7;
  const u16* src = qkv + (size_t)((b * 2048 + s0)) * 6144 + 5120 + kv * 128 + d;
  u16x8 o;
#pragma unroll
  for (int k = 0; k < 8; k++) o[k] = src[(size_t)k * 6144];
  *(u16x8*)(vt + (size_t)(bk * 128 + d) * 2048 + s0) = o;
}

// ---------------- GEMM: C[m,n] = rowscale[m] * sum_k A[m,k]*Bw[n,k] ----------------
__device__ __forceinline__ void store_out(float* p, float v) { *p = v; }
__device__ __forceinline__ void store_out(u16* p, float v) { *p = f2b(v); }

template <typename OutT>
__global__ __launch_bounds__(256) void gemm_bt(const u16* __restrict__ A,
                                               const u16* __restrict__ Bw,
                                               const float* __restrict__ rowscale,
                                               OutT* __restrict__ C,
                                               int M, int N, int K) {
  __shared__ __align__(16) u16 As[128 * 32];
  __shared__ __align__(16) u16 Bs[128 * 32];
  const int tid = threadIdx.x;
  const int lane = tid & 63;
  const int wv = tid >> 6;
  const int wm = wv >> 1, wn = wv & 1;
  const int m0 = blockIdx.y * 128, n0 = blockIdx.x * 128;
  const int g = lane >> 4, c15 = lane & 15;
  f32x4 acc[4][4] = {};

  const int c0 = 2 * wv, c1 = c0 + 1;       // this wave's staging chunks
  const int srow = lane >> 2;               // 0..15 row within chunk
  const int scol = (lane & 3) * 8;          // k offset (elems)
  const u16* Ag0 = A + (size_t)(m0 + c0 * 16 + srow) * K + scol;
  const u16* Ag1 = A + (size_t)(m0 + c1 * 16 + srow) * K + scol;
  const u16* Bg0 = Bw + (size_t)(n0 + c0 * 16 + srow) * K + scol;
  const u16* Bg1 = Bw + (size_t)(n0 + c1 * 16 + srow) * K + scol;
  u16* Al0 = As + c0 * 512 + lane * 8;
  u16* Al1 = As + c1 * 512 + lane * 8;
  u16* Bl0 = Bs + c0 * 512 + lane * 8;
  u16* Bl1 = Bs + c1 * 512 + lane * 8;

  for (int kb = 0; kb < K; kb += 32) {
    __syncthreads();
    async16(Ag0 + kb, Al0);
    async16(Ag1 + kb, Al1);
    async16(Bg0 + kb, Bl0);
    async16(Bg1 + kb, Bl1);
    __syncthreads();
    bf16x8 af[4], bf[4];
#pragma unroll
    for (int i = 0; i < 4; i++) {
      af[i] = ld8(As + (wm * 64 + i * 16 + c15) * 32 + g * 8);
      bf[i] = ld8(Bs + (wn * 64 + i * 16 + c15) * 32 + g * 8);
    }
#pragma unroll
    for (int i = 0; i < 4; i++)
#pragma unroll
      for (int j = 0; j < 4; j++) acc[i][j] = mfma16x16(af[i], bf[j], acc[i][j]);
  }
#pragma unroll
  for (int i = 0; i < 4; i++) {
#pragma unroll
    for (int r = 0; r < 4; r++) {
      int m = m0 + wm * 64 + i * 16 + g * 4 + r;
      float sc = rowscale[m];
#pragma unroll
      for (int j = 0; j < 4; j++) {
        int n = n0 + wn * 64 + j * 16 + c15;
        store_out(C + (size_t)m * N + n, acc[i][j][r] * sc);
      }
    }
  }
}

// ---------------- flash attention (causal, GQA 4:1) ----------------
// grid (S/64, H, B), block 256 (4 waves, 16 q-rows each). 64-key j-tiles.
__global__ __launch_bounds__(256) void attn_kernel(const u16* __restrict__ qkvb,
                                                   const u16* __restrict__ vtb,
                                                   float* __restrict__ out) {
  __shared__ __align__(16) u16 Ks[64 * 128];   // [key][d] 16KB
  __shared__ __align__(16) u16 VTs[128 * 64];  // [d][key] 16KB
  __shared__ __align__(16) u16 Ps[4][16 * 72]; // per-wave P [q][key], stride 72
  const int tid = threadIdx.x, lane = tid & 63, wv = tid >> 6;
  const int q0 = blockIdx.x * 64;
  const int h = blockIdx.y;
  const int b = blockIdx.z;
  const int kvh = h >> 2;
  const int g = lane >> 4, c15 = lane & 15;

  // Q fragments (A-operand): rows q0+wv*16+(lane&15), kept in regs
  bf16x8 qf[4];
  {
    const u16* qp = qkvb + (size_t)(b * 2048 + q0 + wv * 16 + c15) * 6144 + h * 128 + g * 8;
#pragma unroll
    for (int c = 0; c < 4; c++) qf[c] = ld8(qp + c * 32);
  }
  f32x4 acc[8] = {};
  float mrun[4] = {-INFINITY, -INFINITY, -INFINITY, -INFINITY};
  float lrun[4] = {0.f, 0.f, 0.f, 0.f};
  const int qmaxw = q0 + wv * 16 + 15;
  const int nsteps = blockIdx.x + 1;

  // staging pointers: wave wv stages chunks 4wv..4wv+3 of K and VT
  const u16* kg[4]; u16* kl[4];
  const u16* vg[4]; u16* vl[4];
#pragma unroll
  for (int c = 0; c < 4; c++) {
    int ch = 4 * wv + c;
    int key = ch * 4 + (lane >> 4);
    int d0 = (lane & 15) * 8;
    kg[c] = qkvb + (size_t)(b * 2048 + key) * 6144 + 4096 + kvh * 128 + d0;
    kl[c] = Ks + ch * 512 + lane * 8;
    int dd = ch * 8 + (lane >> 3);
    int s0 = (lane & 7) * 8;
    vg[c] = vtb + (size_t)((b * 8 + kvh) * 128 + dd) * 2048 + s0;
    vl[c] = VTs + ch * 512 + lane * 8;
  }

  for (int jt = 0; jt < nsteps; jt++) {
    const int j0 = jt * 64;
    __syncthreads();
#pragma unroll
    for (int c = 0; c < 4; c++) {
      async16(kg[c] + (size_t)j0 * 6144, kl[c]);
      async16(vg[c] + j0, vl[c]);
    }
    __syncthreads();
    // QK^T -> scores (C-layout: col=key, row=q)
    f32x4 sc[4];
#pragma unroll
    for (int nt = 0; nt < 4; nt++) {
      if (j0 + nt * 16 <= qmaxw) {
        f32x4 s = {0.f, 0.f, 0.f, 0.f};
#pragma unroll
        for (int c = 0; c < 4; c++) {
          bf16x8 kf = ld8(Ks + (nt * 16 + c15) * 128 + c * 32 + g * 8);
          s = mfma16x16(qf[c], kf, s);
        }
        int key = j0 + nt * 16 + c15;
#pragma unroll
        for (int r = 0; r < 4; r++) {
          int qi = q0 + wv * 16 + g * 4 + r;
          s[r] = (key <= qi) ? s[r] * 0.08838834764831845f : -INFINITY;
        }
        sc[nt] = s;
      } else {
        sc[nt] = f32x4{-INFINITY, -INFINITY, -INFINITY, -INFINITY};
      }
    }
    // online softmax (per q-row; 16 score cols live across a 16-lane group)
    float p[4][4], alpha[4];
#pragma unroll
    for (int r = 0; r < 4; r++) {
      float rm = fmaxf(fmaxf(sc[0][r], sc[1][r]), fmaxf(sc[2][r], sc[3][r]));
      rm = fmaxf(rm, __shfl_xor(rm, 1));
      rm = fmaxf(rm, __shfl_xor(rm, 2));
      rm = fmaxf(rm, __shfl_xor(rm, 4));
      rm = fmaxf(rm, __shfl_xor(rm, 8));
      float mnew = fmaxf(mrun[r], rm);
      float a = expf(mrun[r] - mnew);
      float rs = 0.f;
#pragma unroll
      for (int nt = 0; nt < 4; nt++) {
        float pv = expf(sc[nt][r] - mnew);
        p[nt][r] = pv;
        rs += pv;
      }
      rs += __shfl_xor(rs, 1);
      rs += __shfl_xor(rs, 2);
      rs += __shfl_xor(rs, 4);
      rs += __shfl_xor(rs, 8);
      lrun[r] = lrun[r] * a + rs;
      mrun[r] = mnew;
      alpha[r] = a;
    }
#pragma unroll
    for (int dt = 0; dt < 8; dt++)
#pragma unroll
      for (int r = 0; r < 4; r++) acc[dt][r] *= alpha[r];
    // P: C-layout -> LDS row-major [q][key] (A-operand layout for PV)
    u16* pw = &Ps[wv][0];
#pragma unroll
    for (int nt = 0; nt < 4; nt++)
#pragma unroll
      for (int r = 0; r < 4; r++)
        pw[(g * 4 + r) * 72 + nt * 16 + c15] = f2b(p[nt][r]);
    __syncthreads();
    // PV: O += P(16x64) * V(64x128)
#pragma unroll
    for (int kc = 0; kc < 2; kc++) {
      bf16x8 pf = ld8(pw + c15 * 72 + kc * 32 + g * 8);
#pragma unroll
      for (int dt = 0; dt < 8; dt++) {
        bf16x8 vf = ld8(VTs + (dt * 16 + c15) * 64 + kc * 32 + g * 8);
        acc[dt] = mfma16x16(pf, vf, acc[dt]);
      }
    }
  }
  // epilogue: normalize and store fp32 attn
#pragma unroll
  for (int r = 0; r < 4; r++) {
    size_t t = (size_t)(b * 2048 + q0 + wv * 16 + g * 4 + r);
    float inv = 1.0f / lrun[r];
    float* op = out + t * 4096 + h * 128;
#pragma unroll
    for (int dt = 0; dt < 8; dt++) op[dt * 16 + c15] = acc[dt][r] * inv;
  }
}

// ---------------- per-row quantization ----------------
__global__ __launch_bounds__(256) void quant_kernel(const float* __restrict__ attn,
                                                    u16* __restrict__ aq,
                                                    float* __restrict__ ascale) {
  const int t = blockIdx.x, tid = threadIdx.x;
  const float* row = attn + (size_t)t * 4096;
  float vals[16];
  float am = 0.f;
#pragma unroll
  for (int i = 0; i < 16; i++) {
    float v = row[tid + i * 256];
    vals[i] = v;
    am = fmaxf(am, fabsf(v));
  }
#pragma unroll
  for (int m = 1; m <= 32; m <<= 1) am = fmaxf(am, __shfl_xor(am, m));
  __shared__ float red[4];
  if ((tid & 63) == 0) red[tid >> 6] = am;
  __syncthreads();
  am = fmaxf(fmaxf(red[0], red[1]), fmaxf(red[2], red[3]));
  float asc = fmaxf(am, 1e-6f) / 127.0f;
  if (tid == 0) ascale[t] = asc;
#pragma unroll
  for (int i = 0; i < 16; i++) {
    float q = rintf(vals[i] / asc);
    q = fminf(127.0f, fmaxf(-127.0f, q));
    aq[(size_t)t * 4096 + tid + i * 256] = f2b(q);  // small ints exact in bf16
  }
}

// ---------------- launch ----------------
extern "C" void kernel_launch(void* const* d_in, const int* in_sizes, int n_in,
                              void* d_out, int out_size, void* d_ws, size_t ws_size,
                              hipStream_t stream) {
  const int* q_hidden = (const int*)d_in[0];
  const float* q_scale = (const float*)d_in[1];
  const int* w_qkv = (const int*)d_in[3];
  const float* s_qkv = (const float*)d_in[4];
  const int* w_o = (const int*)d_in[5];
  const float* s_o = (const float*)d_in[6];
  float* out = (float*)d_out;

  char* ws = (char*)d_ws;
  const size_t MB = 1024 * 1024;
  // ws layout (96 MB peak, regions reused across phases):
  u16* WB = (u16*)(ws);                // [0,48MB) wqkv bf16 (dead after gemm1)
  u16* QKVB = (u16*)(ws + 48 * MB);    // [48,96MB) qkv bf16 (dead after attention)
  u16* VTB = (u16*)(ws);               // [0,8MB) V^T (after gemm1)
  u16* ATTNQ = (u16*)(ws + 8 * MB);    // [8,40MB) attn_q bf16
  float* ASC = (float*)(ws + 40 * MB); // [40MB,+16KB) per-row scales
  u16* WOB = (u16*)(ws + 48 * MB);     // [48,80MB) w_o bf16 (after attention)
  u16* XB = (u16*)d_out;               // x bf16 in d_out (dead after gemm1)

  convert_x<<<16384, 256, 0, stream>>>(q_hidden, XB);
  dequant_w<<<24576, 256, 0, stream>>>(w_qkv, s_qkv, WB);
  gemm_bt<u16><<<dim3(48, 32), 256, 0, stream>>>(XB, WB, q_scale, QKVB,
                                                 T_, OQKV_, HID_);
  rope_kernel<<<40960, 256, 0, stream>>>(QKVB);
  vt_transpose<<<2048, 256, 0, stream>>>(QKVB, VTB);
  attn_kernel<<<dim3(32, 32, 2), 256, 0, stream>>>(QKVB, VTB, out);
  quant_kernel<<<4096, 256, 0, stream>>>(out, ATTNQ, ASC);
  dequant_w<<<16384, 256, 0, stream>>>(w_o, s_o, WOB);
  gemm_bt<float><<<dim3(32, 32), 256, 0, stream>>>(ATTNQ, WOB, ASC, out,
                                                   T_, HID_, HID_);
}

// Round 2
// 1203.900 us; speedup vs baseline: 1.0889x; 1.0889x over previous
//
#include <hip/hip_runtime.h>
#include <math.h>

// Problem constants
#define B_ 2
#define S_ 2048
#define H_ 32
#define KV_ 8
#define D_ 128
#define T_ 4096
#define HID_ 4096
#define OQKV_ 6144

typedef __attribute__((ext_vector_type(4))) float f32x4;
typedef __attribute__((ext_vector_type(8))) __bf16 bf16x8;
typedef __attribute__((ext_vector_type(4))) unsigned short u16x4;
typedef __attribute__((ext_vector_type(8))) unsigned short u16x8;
typedef unsigned short u16;

// float -> bf16 bits, RTNE (finite inputs only)
__device__ __forceinline__ u16 f2b(float f) {
  unsigned x = __float_as_uint(f);
  return (u16)((x + 0x7FFFu + ((x >> 16) & 1u)) >> 16);
}
__device__ __forceinline__ float b2f(u16 u) {
  return __uint_as_float(((unsigned)u) << 16);
}

__device__ __forceinline__ void async16(const void* g, void* l) {
  __builtin_amdgcn_global_load_lds((__attribute__((address_space(1))) void*)g,
                                   (__attribute__((address_space(3))) void*)l,
                                   16, 0, 0);
}

__device__ __forceinline__ bf16x8 ld8(const u16* p) { return *(const bf16x8*)p; }

__device__ __forceinline__ f32x4 mfma16x16(bf16x8 a, bf16x8 b, f32x4 c) {
  return __builtin_amdgcn_mfma_f32_16x16x32_bf16(a, b, c, 0, 0, 0);
}

__device__ __forceinline__ bf16x8 ones8() {
  union { u16x8 u; bf16x8 b; } c;
  c.u = u16x8{0x3F80, 0x3F80, 0x3F80, 0x3F80, 0x3F80, 0x3F80, 0x3F80, 0x3F80};
  return c.b;
}

// ---------------- elementwise kernels ----------------

__global__ __launch_bounds__(256) void convert_x(const int* __restrict__ w,
                                                 u16* __restrict__ out) {
  size_t base = ((size_t)blockIdx.x * 256 + threadIdx.x) * 4;
  int4 v = *(const int4*)(w + base);
  u16x4 o = {f2b((float)v.x), f2b((float)v.y), f2b((float)v.z), f2b((float)v.w)};
  *(u16x4*)(out + base) = o;
}

__global__ __launch_bounds__(256) void dequant_w(const int* __restrict__ w,
                                                 const float* __restrict__ s,
                                                 u16* __restrict__ out) {
  size_t base = ((size_t)blockIdx.x * 256 + threadIdx.x) * 4;
  int row = (int)(base >> 12);
  int col = (int)(base & 4095);
  float sc = s[row * 32 + (col >> 7)];
  int4 v = *(const int4*)(w + base);
  u16x4 o = {f2b(v.x * sc), f2b(v.y * sc), f2b(v.z * sc), f2b(v.w * sc)};
  *(u16x4*)(out + base) = o;
}

// NeoX RoPE in-place on bf16 qkv[t][6144]: q heads 0..31, k heads 32..39
__global__ __launch_bounds__(256) void rope_kernel(u16* __restrict__ qkv) {
  int idx = blockIdx.x * 256 + threadIdx.x;   // T * 40 * 64 total
  int t = idx / 2560;
  int r = idx - t * 2560;
  int head = r >> 6;
  int d = r & 63;
  int col = (head < 32) ? (head * 128 + d) : (4096 + (head - 32) * 128 + d);
  size_t base = (size_t)t * 6144 + col;
  float x1 = b2f(qkv[base]);
  float x2 = b2f(qkv[base + 64]);
  float e = (float)d * 0.015625f;                      // d/64 exact
  float freq = exp2f(e * -19.931568569324174f);        // 1e6^-e
  float ang = (float)(t & 2047) * freq;                // pos = t mod S
  float sn, cs;
  sincosf(ang, &sn, &cs);
  qkv[base] = f2b(x1 * cs - x2 * sn);
  qkv[base + 64] = f2b(x2 * cs + x1 * sn);
}

// V slice of qkv -> VT[b][kv][d][s] via LDS tile transpose. grid (32,2,16).
__global__ __launch_bounds__(256) void vt_transpose(const u16* __restrict__ qkv,
                                                    u16* __restrict__ vt) {
  __shared__ u16 tile[64][65];                 // +1 pad kills bank conflicts
  const int s0 = blockIdx.x * 64, d0 = blockIdx.y * 64;
  const int bk = blockIdx.z, b = bk >> 3, kv = bk & 7;
  const int tid = threadIdx.x;
  const int rr = tid >> 3, cc = tid & 7;
#pragma unroll
  for (int it = 0; it < 2; it++) {
    int r = it * 32 + rr;
    u16x8 v = *(const u16x8*)(qkv + (size_t)(b * 2048 + s0 + r) * 6144 + 5120 +
                              kv * 128 + d0 + cc * 8);
#pragma unroll
    for (int k = 0; k < 8; k++) tile[r][cc * 8 + k] = v[k];
  }
  __syncthreads();
#pragma unroll
  for (int it = 0; it < 2; it++) {
    int d = it * 32 + rr;
    u16x8 o;
#pragma unroll
    for (int k = 0; k < 8; k++) o[k] = tile[cc * 8 + k][d];
    *(u16x8*)(vt + (size_t)(bk * 128 + d0 + d) * 2048 + s0 + cc * 8) = o;
  }
}

// ---------------- GEMM: C[m,n] = rowscale[m] * sum_k A[m,k]*Bw[n,k] ----------------
// LDS chunk XOR swizzle: physical 16B chunk p within a row holds logical
// chunk (p - row) & 3, so fragment reads spread across banks (8-way -> ~2-way).
__device__ __forceinline__ void store_out(float* p, float v) { *p = v; }
__device__ __forceinline__ void store_out(u16* p, float v) { *p = f2b(v); }

template <typename OutT>
__global__ __launch_bounds__(256) void gemm_bt(const u16* __restrict__ A,
                                               const u16* __restrict__ Bw,
                                               const float* __restrict__ rowscale,
                                               OutT* __restrict__ C,
                                               int M, int N, int K) {
  __shared__ __align__(16) u16 As[128 * 32];
  __shared__ __align__(16) u16 Bs[128 * 32];
  const int tid = threadIdx.x;
  const int lane = tid & 63;
  const int wv = tid >> 6;
  const int wm = wv >> 1, wn = wv & 1;
  const int m0 = blockIdx.y * 128, n0 = blockIdx.x * 128;
  const int g = lane >> 4, c15 = lane & 15;
  f32x4 acc[4][4] = {};

  const int c0 = 2 * wv, c1 = c0 + 1;         // this wave's staging chunks
  const int srow = lane >> 2;                 // 0..15 row within chunk
  const int pch = lane & 3;                   // physical 16B chunk slot
  const int scol = (((pch - srow) & 3)) * 8;  // logical chunk -> global col
  const u16* Ag0 = A + (size_t)(m0 + c0 * 16 + srow) * K + scol;
  const u16* Ag1 = A + (size_t)(m0 + c1 * 16 + srow) * K + scol;
  const u16* Bg0 = Bw + (size_t)(n0 + c0 * 16 + srow) * K + scol;
  const u16* Bg1 = Bw + (size_t)(n0 + c1 * 16 + srow) * K + scol;
  u16* Al0 = As + c0 * 512 + lane * 8;
  u16* Al1 = As + c1 * 512 + lane * 8;
  u16* Bl0 = Bs + c0 * 512 + lane * 8;
  u16* Bl1 = Bs + c1 * 512 + lane * 8;

  for (int kb = 0; kb < K; kb += 32) {
    __syncthreads();
    async16(Ag0 + kb, Al0);
    async16(Ag1 + kb, Al1);
    async16(Bg0 + kb, Bl0);
    async16(Bg1 + kb, Bl1);
    __syncthreads();
    bf16x8 af[4], bf[4];
#pragma unroll
    for (int i = 0; i < 4; i++) {
      af[i] = ld8(As + (wm * 64 + i * 16 + c15) * 32 + ((g + c15) & 3) * 8);
      bf[i] = ld8(Bs + (wn * 64 + i * 16 + c15) * 32 + ((g + c15) & 3) * 8);
    }
#pragma unroll
    for (int i = 0; i < 4; i++)
#pragma unroll
      for (int j = 0; j < 4; j++) acc[i][j] = mfma16x16(af[i], bf[j], acc[i][j]);
  }
#pragma unroll
  for (int i = 0; i < 4; i++) {
#pragma unroll
    for (int r = 0; r < 4; r++) {
      int m = m0 + wm * 64 + i * 16 + g * 4 + r;
      float sc = rowscale[m];
#pragma unroll
      for (int j = 0; j < 4; j++) {
        int n = n0 + wn * 64 + j * 16 + c15;
        store_out(C + (size_t)m * N + n, acc[i][j][r] * sc);
      }
    }
  }
}

// ---------------- flash attention (causal, GQA 4:1) ----------------
// Barrier-free: each wave owns 32 q-rows and loads K/V fragments directly
// from global (L2-resident; K/V slice shared by 4 heads). Only the P
// C-layout -> A-layout transform round-trips wave-private LDS (lgkmcnt only).
// Row-sum l comes from an extra MFMA against an all-ones B fragment (acc[8]),
// which auto-rescales with alpha. grid (16, 32, 2), block 256.
__global__ __launch_bounds__(256, 2) void attn_kernel(const u16* __restrict__ qkvb,
                                                      const u16* __restrict__ vtb,
                                                      float* __restrict__ out) {
  __shared__ __align__(16) u16 Ps[4][2][16 * 72];   // per-wave, per-m-tile P
  const int tid = threadIdx.x, lane = tid & 63, wv = tid >> 6;
  const int g = lane >> 4, c15 = lane & 15;
  const int qt = 63 - (blockIdx.x * 4 + wv);        // heavy q-tiles first
  const int q0 = qt * 32;
  const int h = blockIdx.y, b = blockIdx.z, kvh = h >> 2;

  bf16x8 qf[2][4];
#pragma unroll
  for (int m = 0; m < 2; m++) {
    const u16* qp =
        qkvb + (size_t)(b * 2048 + q0 + m * 16 + c15) * 6144 + h * 128 + g * 8;
#pragma unroll
    for (int c = 0; c < 4; c++) qf[m][c] = ld8(qp + c * 32);
  }
  f32x4 acc[2][9] = {};
  float mrun[2][4] = {{-INFINITY, -INFINITY, -INFINITY, -INFINITY},
                      {-INFINITY, -INFINITY, -INFINITY, -INFINITY}};
  const int qmax = q0 + 31;
  const int nsteps = qt / 2 + 1;
  const bf16x8 vones = ones8();
  const u16* kbase = qkvb + (size_t)(b * 2048 + c15) * 6144 + 4096 + kvh * 128 + g * 8;
  const u16* vbase = vtb + (size_t)((b * 8 + kvh) * 128 + c15) * 2048 + g * 8;
  u16* pw0 = &Ps[wv][0][0];
  u16* pw1 = &Ps[wv][1][0];

  for (int jt = 0; jt < nsteps; jt++) {
    const int j0 = jt * 64;
    f32x4 sc[2][4];
    // QK^T: K fragments straight from global (16 x b128 loads, L2-hot)
#pragma unroll
    for (int nt = 0; nt < 4; nt++) {
      if (j0 + nt * 16 <= qmax) {
        bf16x8 kf[4];
        const u16* kp = kbase + (size_t)(j0 + nt * 16) * 6144;
#pragma unroll
        for (int c = 0; c < 4; c++) kf[c] = ld8(kp + c * 32);
        f32x4 s0 = {0.f, 0.f, 0.f, 0.f}, s1 = {0.f, 0.f, 0.f, 0.f};
#pragma unroll
        for (int c = 0; c < 4; c++) {
          s0 = mfma16x16(qf[0][c], kf[c], s0);
          s1 = mfma16x16(qf[1][c], kf[c], s1);
        }
        const int key = j0 + nt * 16 + c15;
#pragma unroll
        for (int r = 0; r < 4; r++) {
          sc[0][nt][r] =
              (key <= q0 + g * 4 + r) ? s0[r] * 0.08838834764831845f : -INFINITY;
          sc[1][nt][r] =
              (key <= q0 + 16 + g * 4 + r) ? s1[r] * 0.08838834764831845f : -INFINITY;
        }
      }
    }
    // online softmax per m-tile (masked nt tiles: p = 0, no exp)
#pragma unroll
    for (int m = 0; m < 2; m++) {
      u16* pw = m ? pw1 : pw0;
      float alpha[4];
#pragma unroll
      for (int r = 0; r < 4; r++) {
        float rm = -INFINITY;
#pragma unroll
        for (int nt = 0; nt < 4; nt++)
          if (j0 + nt * 16 <= qmax) rm = fmaxf(rm, sc[m][nt][r]);
        rm = fmaxf(rm, __shfl_xor(rm, 1));
        rm = fmaxf(rm, __shfl_xor(rm, 2));
        rm = fmaxf(rm, __shfl_xor(rm, 4));
        rm = fmaxf(rm, __shfl_xor(rm, 8));
        float mnew = fmaxf(mrun[m][r], rm);
        alpha[r] = __expf(mrun[m][r] - mnew);
        mrun[m][r] = mnew;
#pragma unroll
        for (int nt = 0; nt < 4; nt++) {
          float pv = (j0 + nt * 16 <= qmax) ? __expf(sc[m][nt][r] - mnew) : 0.0f;
          pw[(g * 4 + r) * 72 + nt * 16 + c15] = f2b(pv);
        }
      }
#pragma unroll
      for (int dt = 0; dt < 9; dt++)
#pragma unroll
        for (int r = 0; r < 4; r++) acc[m][dt][r] *= alpha[r];
    }
    // PV: V fragments straight from global; ones-column accumulates l
#pragma unroll
    for (int kc = 0; kc < 2; kc++) {
      bf16x8 pf0 = ld8(pw0 + c15 * 72 + kc * 32 + g * 8);
      bf16x8 pf1 = ld8(pw1 + c15 * 72 + kc * 32 + g * 8);
#pragma unroll
      for (int dt = 0; dt < 8; dt++) {
        bf16x8 vf = ld8(vbase + (size_t)(dt * 16) * 2048 + j0 + kc * 32);
        acc[0][dt] = mfma16x16(pf0, vf, acc[0][dt]);
        acc[1][dt] = mfma16x16(pf1, vf, acc[1][dt]);
      }
      acc[0][8] = mfma16x16(pf0, vones, acc[0][8]);
      acc[1][8] = mfma16x16(pf1, vones, acc[1][8]);
    }
  }
  // epilogue: normalize by l (= acc[8], replicated across c15) and store fp32
#pragma unroll
  for (int m = 0; m < 2; m++)
#pragma unroll
    for (int r = 0; r < 4; r++) {
      const int row = q0 + m * 16 + g * 4 + r;
      float inv = 1.0f / acc[m][8][r];
      float* op = out + (size_t)(b * 2048 + row) * 4096 + h * 128;
#pragma unroll
      for (int dt = 0; dt < 8; dt++) op[dt * 16 + c15] = acc[m][dt][r] * inv;
    }
}

// ---------------- per-row quantization ----------------
__global__ __launch_bounds__(256) void quant_kernel(const float* __restrict__ attn,
                                                    u16* __restrict__ aq,
                                                    float* __restrict__ ascale) {
  const int t = blockIdx.x, tid = threadIdx.x;
  const float* row = attn + (size_t)t * 4096;
  float vals[16];
  float am = 0.f;
#pragma unroll
  for (int i = 0; i < 16; i++) {
    float v = row[tid + i * 256];
    vals[i] = v;
    am = fmaxf(am, fabsf(v));
  }
#pragma unroll
  for (int m = 1; m <= 32; m <<= 1) am = fmaxf(am, __shfl_xor(am, m));
  __shared__ float red[4];
  if ((tid & 63) == 0) red[tid >> 6] = am;
  __syncthreads();
  am = fmaxf(fmaxf(red[0], red[1]), fmaxf(red[2], red[3]));
  float asc = fmaxf(am, 1e-6f) / 127.0f;
  if (tid == 0) ascale[t] = asc;
#pragma unroll
  for (int i = 0; i < 16; i++) {
    float q = rintf(vals[i] / asc);
    q = fminf(127.0f, fmaxf(-127.0f, q));
    aq[(size_t)t * 4096 + tid + i * 256] = f2b(q);  // small ints exact in bf16
  }
}

// ---------------- launch ----------------
extern "C" void kernel_launch(void* const* d_in, const int* in_sizes, int n_in,
                              void* d_out, int out_size, void* d_ws, size_t ws_size,
                              hipStream_t stream) {
  const int* q_hidden = (const int*)d_in[0];
  const float* q_scale = (const float*)d_in[1];
  const int* w_qkv = (const int*)d_in[3];
  const float* s_qkv = (const float*)d_in[4];
  const int* w_o = (const int*)d_in[5];
  const float* s_o = (const float*)d_in[6];
  float* out = (float*)d_out;

  char* ws = (char*)d_ws;
  const size_t MB = 1024 * 1024;
  // ws layout (96 MB peak, regions reused across phases):
  u16* WB = (u16*)(ws);                // [0,48MB) wqkv bf16 (dead after gemm1)
  u16* QKVB = (u16*)(ws + 48 * MB);    // [48,96MB) qkv bf16 (dead after attention)
  u16* VTB = (u16*)(ws);               // [0,8MB) V^T (after gemm1)
  u16* ATTNQ = (u16*)(ws + 8 * MB);    // [8,40MB) attn_q bf16
  float* ASC = (float*)(ws + 40 * MB); // [40MB,+16KB) per-row scales
  u16* WOB = (u16*)(ws + 48 * MB);     // [48,80MB) w_o bf16 (after attention)
  u16* XB = (u16*)d_out;               // x bf16 in d_out (dead after gemm1)

  convert_x<<<16384, 256, 0, stream>>>(q_hidden, XB);
  dequant_w<<<24576, 256, 0, stream>>>(w_qkv, s_qkv, WB);
  gemm_bt<u16><<<dim3(48, 32), 256, 0, stream>>>(XB, WB, q_scale, QKVB,
                                                 T_, OQKV_, HID_);
  rope_kernel<<<40960, 256, 0, stream>>>(QKVB);
  vt_transpose<<<dim3(32, 2, 16), 256, 0, stream>>>(QKVB, VTB);
  attn_kernel<<<dim3(16, 32, 2), 256, 0, stream>>>(QKVB, VTB, out);
  quant_kernel<<<4096, 256, 0, stream>>>(out, ATTNQ, ASC);
  dequant_w<<<16384, 256, 0, stream>>>(w_o, s_o, WOB);
  gemm_bt<float><<<dim3(32, 32), 256, 0, stream>>>(ATTNQ, WOB, ASC, out,
                                                   T_, HID_, HID_);
}

// Round 3
// 1097.717 us; speedup vs baseline: 1.1942x; 1.0967x over previous
//
#include <hip/hip_runtime.h>
#include <math.h>

// Problem constants
#define B_ 2
#define S_ 2048
#define H_ 32
#define KV_ 8
#define D_ 128
#define T_ 4096
#define HID_ 4096
#define OQKV_ 6144

typedef __attribute__((ext_vector_type(4))) float f32x4;
typedef __attribute__((ext_vector_type(8))) __bf16 bf16x8;
typedef __attribute__((ext_vector_type(4))) unsigned short u16x4;
typedef __attribute__((ext_vector_type(8))) unsigned short u16x8;
typedef unsigned short u16;

// float -> bf16 bits, RTNE (finite inputs only)
__device__ __forceinline__ u16 f2b(float f) {
  unsigned x = __float_as_uint(f);
  return (u16)((x + 0x7FFFu + ((x >> 16) & 1u)) >> 16);
}
__device__ __forceinline__ float b2f(u16 u) {
  return __uint_as_float(((unsigned)u) << 16);
}

__device__ __forceinline__ void async16(const void* g, void* l) {
  __builtin_amdgcn_global_load_lds((__attribute__((address_space(1))) void*)g,
                                   (__attribute__((address_space(3))) void*)l,
                                   16, 0, 0);
}

__device__ __forceinline__ bf16x8 ld8(const u16* p) { return *(const bf16x8*)p; }

__device__ __forceinline__ f32x4 mfma16x16(bf16x8 a, bf16x8 b, f32x4 c) {
  return __builtin_amdgcn_mfma_f32_16x16x32_bf16(a, b, c, 0, 0, 0);
}

__device__ __forceinline__ bf16x8 ones8() {
  union { u16x8 u; bf16x8 b; } c;
  c.u = u16x8{0x3F80, 0x3F80, 0x3F80, 0x3F80, 0x3F80, 0x3F80, 0x3F80, 0x3F80};
  return c.b;
}

// ---------------- elementwise kernels ----------------

__global__ __launch_bounds__(256) void convert_x(const int* __restrict__ w,
                                                 u16* __restrict__ out) {
  size_t base = ((size_t)blockIdx.x * 256 + threadIdx.x) * 4;
  int4 v = *(const int4*)(w + base);
  u16x4 o = {f2b((float)v.x), f2b((float)v.y), f2b((float)v.z), f2b((float)v.w)};
  *(u16x4*)(out + base) = o;
}

__global__ __launch_bounds__(256) void dequant_w(const int* __restrict__ w,
                                                 const float* __restrict__ s,
                                                 u16* __restrict__ out) {
  size_t base = ((size_t)blockIdx.x * 256 + threadIdx.x) * 4;
  int row = (int)(base >> 12);
  int col = (int)(base & 4095);
  float sc = s[row * 32 + (col >> 7)];
  int4 v = *(const int4*)(w + base);
  u16x4 o = {f2b(v.x * sc), f2b(v.y * sc), f2b(v.z * sc), f2b(v.w * sc)};
  *(u16x4*)(out + base) = o;
}

// NeoX RoPE in-place on bf16 qkv[t][6144]: q heads 0..31, k heads 32..39
__global__ __launch_bounds__(256) void rope_kernel(u16* __restrict__ qkv) {
  int idx = blockIdx.x * 256 + threadIdx.x;   // T * 40 * 64 total
  int t = idx / 2560;
  int r = idx - t * 2560;
  int head = r >> 6;
  int d = r & 63;
  int col = (head < 32) ? (head * 128 + d) : (4096 + (head - 32) * 128 + d);
  size_t base = (size_t)t * 6144 + col;
  float x1 = b2f(qkv[base]);
  float x2 = b2f(qkv[base + 64]);
  float e = (float)d * 0.015625f;                      // d/64 exact
  float freq = exp2f(e * -19.931568569324174f);        // 1e6^-e
  float ang = (float)(t & 2047) * freq;                // pos = t mod S
  float sn, cs;
  sincosf(ang, &sn, &cs);
  qkv[base] = f2b(x1 * cs - x2 * sn);
  qkv[base + 64] = f2b(x2 * cs + x1 * sn);
}

// V slice of qkv -> VT[b][kv][d][s] via LDS tile transpose. grid (32,2,16).
__global__ __launch_bounds__(256) void vt_transpose(const u16* __restrict__ qkv,
                                                    u16* __restrict__ vt) {
  __shared__ u16 tile[64][65];                 // +1 pad kills bank conflicts
  const int s0 = blockIdx.x * 64, d0 = blockIdx.y * 64;
  const int bk = blockIdx.z, b = bk >> 3, kv = bk & 7;
  const int tid = threadIdx.x;
  const int rr = tid >> 3, cc = tid & 7;
#pragma unroll
  for (int it = 0; it < 2; it++) {
    int r = it * 32 + rr;
    u16x8 v = *(const u16x8*)(qkv + (size_t)(b * 2048 + s0 + r) * 6144 + 5120 +
                              kv * 128 + d0 + cc * 8);
#pragma unroll
    for (int k = 0; k < 8; k++) tile[r][cc * 8 + k] = v[k];
  }
  __syncthreads();
#pragma unroll
  for (int it = 0; it < 2; it++) {
    int d = it * 32 + rr;
    u16x8 o;
#pragma unroll
    for (int k = 0; k < 8; k++) o[k] = tile[cc * 8 + k][d];
    *(u16x8*)(vt + (size_t)(bk * 128 + d0 + d) * 2048 + s0 + cc * 8) = o;
  }
}

// ---------------- GEMM: C[m,n] = rowscale[m] * sum_k A[m,k]*Bw[n,k] ----------------
// LDS chunk XOR swizzle: physical 16B chunk p within a row holds logical
// chunk (p - row) & 3, so fragment reads spread across banks (8-way -> ~2-way).
__device__ __forceinline__ void store_out(float* p, float v) { *p = v; }
__device__ __forceinline__ void store_out(u16* p, float v) { *p = f2b(v); }

template <typename OutT>
__global__ __launch_bounds__(256) void gemm_bt(const u16* __restrict__ A,
                                               const u16* __restrict__ Bw,
                                               const float* __restrict__ rowscale,
                                               OutT* __restrict__ C,
                                               int M, int N, int K) {
  __shared__ __align__(16) u16 As[128 * 32];
  __shared__ __align__(16) u16 Bs[128 * 32];
  const int tid = threadIdx.x;
  const int lane = tid & 63;
  const int wv = tid >> 6;
  const int wm = wv >> 1, wn = wv & 1;
  const int m0 = blockIdx.y * 128, n0 = blockIdx.x * 128;
  const int g = lane >> 4, c15 = lane & 15;
  f32x4 acc[4][4] = {};

  const int c0 = 2 * wv, c1 = c0 + 1;         // this wave's staging chunks
  const int srow = lane >> 2;                 // 0..15 row within chunk
  const int pch = lane & 3;                   // physical 16B chunk slot
  const int scol = (((pch - srow) & 3)) * 8;  // logical chunk -> global col
  const u16* Ag0 = A + (size_t)(m0 + c0 * 16 + srow) * K + scol;
  const u16* Ag1 = A + (size_t)(m0 + c1 * 16 + srow) * K + scol;
  const u16* Bg0 = Bw + (size_t)(n0 + c0 * 16 + srow) * K + scol;
  const u16* Bg1 = Bw + (size_t)(n0 + c1 * 16 + srow) * K + scol;
  u16* Al0 = As + c0 * 512 + lane * 8;
  u16* Al1 = As + c1 * 512 + lane * 8;
  u16* Bl0 = Bs + c0 * 512 + lane * 8;
  u16* Bl1 = Bs + c1 * 512 + lane * 8;

  for (int kb = 0; kb < K; kb += 32) {
    __syncthreads();
    async16(Ag0 + kb, Al0);
    async16(Ag1 + kb, Al1);
    async16(Bg0 + kb, Bl0);
    async16(Bg1 + kb, Bl1);
    __syncthreads();
    bf16x8 af[4], bf[4];
#pragma unroll
    for (int i = 0; i < 4; i++) {
      af[i] = ld8(As + (wm * 64 + i * 16 + c15) * 32 + ((g + c15) & 3) * 8);
      bf[i] = ld8(Bs + (wn * 64 + i * 16 + c15) * 32 + ((g + c15) & 3) * 8);
    }
#pragma unroll
    for (int i = 0; i < 4; i++)
#pragma unroll
      for (int j = 0; j < 4; j++) acc[i][j] = mfma16x16(af[i], bf[j], acc[i][j]);
  }
#pragma unroll
  for (int i = 0; i < 4; i++) {
#pragma unroll
    for (int r = 0; r < 4; r++) {
      int m = m0 + wm * 64 + i * 16 + g * 4 + r;
      float sc = rowscale[m];
#pragma unroll
      for (int j = 0; j < 4; j++) {
        int n = n0 + wn * 64 + j * 16 + c15;
        store_out(C + (size_t)m * N + n, acc[i][j][r] * sc);
      }
    }
  }
}

// ---------------- flash attention (causal, GQA 4:1) ----------------
// Barrier-free: each wave owns 32 q-rows and loads K/V fragments directly
// from global (L2-resident; K/V slice shared by 4 heads). Only the P
// C-layout -> A-layout transform round-trips wave-private LDS (lgkmcnt only).
// Row-sum l comes from an extra MFMA against an all-ones B fragment (acc[8]).
//
// Load balance: wave wv of block x handles q-tile from quadrant (wv+x)&3 with
// offset a=x: tiles {a, 31-a, 32+a, 63-a}. Bijective over the 64 tiles, every
// block totals ~67 steps (constant), and the rotation keeps any one SIMD slot
// from hoarding the heavy quadrant. grid (16, 32, 2), block 256.
__global__ __launch_bounds__(256, 2) void attn_kernel(const u16* __restrict__ qkvb,
                                                      const u16* __restrict__ vtb,
                                                      float* __restrict__ out) {
  __shared__ __align__(16) u16 Ps[4][2][16 * 72];   // per-wave, per-m-tile P
  const int tid = threadIdx.x, lane = tid & 63, wv = tid >> 6;
  const int g = lane >> 4, c15 = lane & 15;
  const int x = blockIdx.x;                         // 0..15
  const int qsel = (wv + x) & 3;
  const int qt = (qsel == 0) ? x : (qsel == 1) ? 31 - x
               : (qsel == 2) ? 32 + x : 63 - x;
  const int q0 = qt * 32;
  const int h = blockIdx.y, b = blockIdx.z, kvh = h >> 2;

  bf16x8 qf[2][4];
#pragma unroll
  for (int m = 0; m < 2; m++) {
    const u16* qp =
        qkvb + (size_t)(b * 2048 + q0 + m * 16 + c15) * 6144 + h * 128 + g * 8;
#pragma unroll
    for (int c = 0; c < 4; c++) qf[m][c] = ld8(qp + c * 32);
  }
  f32x4 acc[2][9] = {};
  float mrun[2][4] = {{-INFINITY, -INFINITY, -INFINITY, -INFINITY},
                      {-INFINITY, -INFINITY, -INFINITY, -INFINITY}};
  const int qmax = q0 + 31;
  const int nsteps = qt / 2 + 1;
  const bf16x8 vones = ones8();
  const u16* kbase = qkvb + (size_t)(b * 2048 + c15) * 6144 + 4096 + kvh * 128 + g * 8;
  const u16* vbase = vtb + (size_t)((b * 8 + kvh) * 128 + c15) * 2048 + g * 8;
  u16* pw0 = &Ps[wv][0][0];
  u16* pw1 = &Ps[wv][1][0];

  for (int jt = 0; jt < nsteps; jt++) {
    const int j0 = jt * 64;
    f32x4 sc[2][4];
    // QK^T: K fragments straight from global (16 x b128 loads, L2-hot)
#pragma unroll
    for (int nt = 0; nt < 4; nt++) {
      if (j0 + nt * 16 <= qmax) {
        bf16x8 kf[4];
        const u16* kp = kbase + (size_t)(j0 + nt * 16) * 6144;
#pragma unroll
        for (int c = 0; c < 4; c++) kf[c] = ld8(kp + c * 32);
        f32x4 s0 = {0.f, 0.f, 0.f, 0.f}, s1 = {0.f, 0.f, 0.f, 0.f};
#pragma unroll
        for (int c = 0; c < 4; c++) {
          s0 = mfma16x16(qf[0][c], kf[c], s0);
          s1 = mfma16x16(qf[1][c], kf[c], s1);
        }
        const int key = j0 + nt * 16 + c15;
#pragma unroll
        for (int r = 0; r < 4; r++) {
          sc[0][nt][r] =
              (key <= q0 + g * 4 + r) ? s0[r] * 0.08838834764831845f : -INFINITY;
          sc[1][nt][r] =
              (key <= q0 + 16 + g * 4 + r) ? s1[r] * 0.08838834764831845f : -INFINITY;
        }
      }
    }
    // online softmax per m-tile (masked nt tiles: p = 0, no exp)
#pragma unroll
    for (int m = 0; m < 2; m++) {
      u16* pw = m ? pw1 : pw0;
      float alpha[4];
#pragma unroll
      for (int r = 0; r < 4; r++) {
        float rm = -INFINITY;
#pragma unroll
        for (int nt = 0; nt < 4; nt++)
          if (j0 + nt * 16 <= qmax) rm = fmaxf(rm, sc[m][nt][r]);
        rm = fmaxf(rm, __shfl_xor(rm, 1));
        rm = fmaxf(rm, __shfl_xor(rm, 2));
        rm = fmaxf(rm, __shfl_xor(rm, 4));
        rm = fmaxf(rm, __shfl_xor(rm, 8));
        float mnew = fmaxf(mrun[m][r], rm);
        alpha[r] = __expf(mrun[m][r] - mnew);
        mrun[m][r] = mnew;
#pragma unroll
        for (int nt = 0; nt < 4; nt++) {
          float pv = (j0 + nt * 16 <= qmax) ? __expf(sc[m][nt][r] - mnew) : 0.0f;
          pw[(g * 4 + r) * 72 + nt * 16 + c15] = f2b(pv);
        }
      }
#pragma unroll
      for (int dt = 0; dt < 9; dt++)
#pragma unroll
        for (int r = 0; r < 4; r++) acc[m][dt][r] *= alpha[r];
    }
    // PV: V fragments straight from global; ones-column accumulates l
#pragma unroll
    for (int kc = 0; kc < 2; kc++) {
      bf16x8 pf0 = ld8(pw0 + c15 * 72 + kc * 32 + g * 8);
      bf16x8 pf1 = ld8(pw1 + c15 * 72 + kc * 32 + g * 8);
#pragma unroll
      for (int dt = 0; dt < 8; dt++) {
        bf16x8 vf = ld8(vbase + (size_t)(dt * 16) * 2048 + j0 + kc * 32);
        acc[0][dt] = mfma16x16(pf0, vf, acc[0][dt]);
        acc[1][dt] = mfma16x16(pf1, vf, acc[1][dt]);
      }
      acc[0][8] = mfma16x16(pf0, vones, acc[0][8]);
      acc[1][8] = mfma16x16(pf1, vones, acc[1][8]);
    }
  }
  // epilogue: normalize by l (= acc[8], replicated across c15) and store fp32
#pragma unroll
  for (int m = 0; m < 2; m++)
#pragma unroll
    for (int r = 0; r < 4; r++) {
      const int row = q0 + m * 16 + g * 4 + r;
      float inv = 1.0f / acc[m][8][r];
      float* op = out + (size_t)(b * 2048 + row) * 4096 + h * 128;
#pragma unroll
      for (int dt = 0; dt < 8; dt++) op[dt * 16 + c15] = acc[m][dt][r] * inv;
    }
}

// ---------------- per-row quantization ----------------
__global__ __launch_bounds__(256) void quant_kernel(const float* __restrict__ attn,
                                                    u16* __restrict__ aq,
                                                    float* __restrict__ ascale) {
  const int t = blockIdx.x, tid = threadIdx.x;
  const float* row = attn + (size_t)t * 4096;
  float vals[16];
  float am = 0.f;
#pragma unroll
  for (int i = 0; i < 16; i++) {
    float v = row[tid + i * 256];
    vals[i] = v;
    am = fmaxf(am, fabsf(v));
  }
#pragma unroll
  for (int m = 1; m <= 32; m <<= 1) am = fmaxf(am, __shfl_xor(am, m));
  __shared__ float red[4];
  if ((tid & 63) == 0) red[tid >> 6] = am;
  __syncthreads();
  am = fmaxf(fmaxf(red[0], red[1]), fmaxf(red[2], red[3]));
  float asc = fmaxf(am, 1e-6f) / 127.0f;
  if (tid == 0) ascale[t] = asc;
#pragma unroll
  for (int i = 0; i < 16; i++) {
    float q = rintf(vals[i] / asc);
    q = fminf(127.0f, fmaxf(-127.0f, q));
    aq[(size_t)t * 4096 + tid + i * 256] = f2b(q);  // small ints exact in bf16
  }
}

// ---------------- launch ----------------
extern "C" void kernel_launch(void* const* d_in, const int* in_sizes, int n_in,
                              void* d_out, int out_size, void* d_ws, size_t ws_size,
                              hipStream_t stream) {
  const int* q_hidden = (const int*)d_in[0];
  const float* q_scale = (const float*)d_in[1];
  const int* w_qkv = (const int*)d_in[3];
  const float* s_qkv = (const float*)d_in[4];
  const int* w_o = (const int*)d_in[5];
  const float* s_o = (const float*)d_in[6];
  float* out = (float*)d_out;

  char* ws = (char*)d_ws;
  const size_t MB = 1024 * 1024;
  // ws layout (96 MB peak, regions reused across phases):
  u16* WB = (u16*)(ws);                // [0,48MB) wqkv bf16 (dead after gemm1)
  u16* QKVB = (u16*)(ws + 48 * MB);    // [48,96MB) qkv bf16 (dead after attention)
  u16* VTB = (u16*)(ws);               // [0,8MB) V^T (after gemm1)
  u16* ATTNQ = (u16*)(ws + 8 * MB);    // [8,40MB) attn_q bf16
  float* ASC = (float*)(ws + 40 * MB); // [40MB,+16KB) per-row scales
  u16* WOB = (u16*)(ws + 48 * MB);     // [48,80MB) w_o bf16 (after attention)
  u16* XB = (u16*)d_out;               // x bf16 in d_out (dead after gemm1)

  convert_x<<<16384, 256, 0, stream>>>(q_hidden, XB);
  dequant_w<<<24576, 256, 0, stream>>>(w_qkv, s_qkv, WB);
  gemm_bt<u16><<<dim3(48, 32), 256, 0, stream>>>(XB, WB, q_scale, QKVB,
                                                 T_, OQKV_, HID_);
  rope_kernel<<<40960, 256, 0, stream>>>(QKVB);
  vt_transpose<<<dim3(32, 2, 16), 256, 0, stream>>>(QKVB, VTB);
  attn_kernel<<<dim3(16, 32, 2), 256, 0, stream>>>(QKVB, VTB, out);
  quant_kernel<<<4096, 256, 0, stream>>>(out, ATTNQ, ASC);
  dequant_w<<<16384, 256, 0, stream>>>(w_o, s_o, WOB);
  gemm_bt<float><<<dim3(32, 32), 256, 0, stream>>>(ATTNQ, WOB, ASC, out,
                                                   T_, HID_, HID_);
}

// Round 4
// 973.265 us; speedup vs baseline: 1.3469x; 1.1279x over previous
//
#include <hip/hip_runtime.h>
#include <math.h>

// Problem constants
#define B_ 2
#define S_ 2048
#define H_ 32
#define KV_ 8
#define D_ 128
#define T_ 4096
#define HID_ 4096
#define OQKV_ 6144

typedef __attribute__((ext_vector_type(4))) float f32x4;
typedef __attribute__((ext_vector_type(8))) __bf16 bf16x8;
typedef __attribute__((ext_vector_type(4))) unsigned short u16x4;
typedef __attribute__((ext_vector_type(8))) unsigned short u16x8;
typedef unsigned short u16;

// float -> bf16 bits, RTNE (finite inputs only)
__device__ __forceinline__ u16 f2b(float f) {
  unsigned x = __float_as_uint(f);
  return (u16)((x + 0x7FFFu + ((x >> 16) & 1u)) >> 16);
}
__device__ __forceinline__ float b2f(u16 u) {
  return __uint_as_float(((unsigned)u) << 16);
}

__device__ __forceinline__ void async16(const void* g, void* l) {
  __builtin_amdgcn_global_load_lds((__attribute__((address_space(1))) void*)g,
                                   (__attribute__((address_space(3))) void*)l,
                                   16, 0, 0);
}

__device__ __forceinline__ bf16x8 ld8(const u16* p) { return *(const bf16x8*)p; }

__device__ __forceinline__ f32x4 mfma16x16(bf16x8 a, bf16x8 b, f32x4 c) {
  return __builtin_amdgcn_mfma_f32_16x16x32_bf16(a, b, c, 0, 0, 0);
}

__device__ __forceinline__ bf16x8 ones8() {
  union { u16x8 u; bf16x8 b; } c;
  c.u = u16x8{0x3F80, 0x3F80, 0x3F80, 0x3F80, 0x3F80, 0x3F80, 0x3F80, 0x3F80};
  return c.b;
}

// ---------------- elementwise kernels ----------------

__global__ __launch_bounds__(256) void convert_x(const int* __restrict__ w,
                                                 u16* __restrict__ out) {
  size_t base = ((size_t)blockIdx.x * 256 + threadIdx.x) * 4;
  int4 v = *(const int4*)(w + base);
  u16x4 o = {f2b((float)v.x), f2b((float)v.y), f2b((float)v.z), f2b((float)v.w)};
  *(u16x4*)(out + base) = o;
}

__global__ __launch_bounds__(256) void dequant_w(const int* __restrict__ w,
                                                 const float* __restrict__ s,
                                                 u16* __restrict__ out) {
  size_t base = ((size_t)blockIdx.x * 256 + threadIdx.x) * 4;
  int row = (int)(base >> 12);
  int col = (int)(base & 4095);
  float sc = s[row * 32 + (col >> 7)];
  int4 v = *(const int4*)(w + base);
  u16x4 o = {f2b(v.x * sc), f2b(v.y * sc), f2b(v.z * sc), f2b(v.w * sc)};
  *(u16x4*)(out + base) = o;
}

// NeoX RoPE in-place on bf16 qkv[t][6144]: q heads 0..31, k heads 32..39
__global__ __launch_bounds__(256) void rope_kernel(u16* __restrict__ qkv) {
  int idx = blockIdx.x * 256 + threadIdx.x;   // T * 40 * 64 total
  int t = idx / 2560;
  int r = idx - t * 2560;
  int head = r >> 6;
  int d = r & 63;
  int col = (head < 32) ? (head * 128 + d) : (4096 + (head - 32) * 128 + d);
  size_t base = (size_t)t * 6144 + col;
  float x1 = b2f(qkv[base]);
  float x2 = b2f(qkv[base + 64]);
  float e = (float)d * 0.015625f;                      // d/64 exact
  float freq = exp2f(e * -19.931568569324174f);        // 1e6^-e
  float ang = (float)(t & 2047) * freq;                // pos = t mod S
  float sn, cs;
  sincosf(ang, &sn, &cs);
  qkv[base] = f2b(x1 * cs - x2 * sn);
  qkv[base + 64] = f2b(x2 * cs + x1 * sn);
}

// V slice of qkv -> VT[b][kv][d][s] via LDS tile transpose. grid (32,2,16).
__global__ __launch_bounds__(256) void vt_transpose(const u16* __restrict__ qkv,
                                                    u16* __restrict__ vt) {
  __shared__ u16 tile[64][65];                 // +1 pad kills bank conflicts
  const int s0 = blockIdx.x * 64, d0 = blockIdx.y * 64;
  const int bk = blockIdx.z, b = bk >> 3, kv = bk & 7;
  const int tid = threadIdx.x;
  const int rr = tid >> 3, cc = tid & 7;
#pragma unroll
  for (int it = 0; it < 2; it++) {
    int r = it * 32 + rr;
    u16x8 v = *(const u16x8*)(qkv + (size_t)(b * 2048 + s0 + r) * 6144 + 5120 +
                              kv * 128 + d0 + cc * 8);
#pragma unroll
    for (int k = 0; k < 8; k++) tile[r][cc * 8 + k] = v[k];
  }
  __syncthreads();
#pragma unroll
  for (int it = 0; it < 2; it++) {
    int d = it * 32 + rr;
    u16x8 o;
#pragma unroll
    for (int k = 0; k < 8; k++) o[k] = tile[cc * 8 + k][d];
    *(u16x8*)(vt + (size_t)(bk * 128 + d0 + d) * 2048 + s0 + cc * 8) = o;
  }
}

// ---------------- GEMM: C[m,n] = rowscale[m] * sum_k A[m,k]*Bw[n,k] ----------------
// LDS chunk XOR swizzle: physical 16B chunk p within a row holds logical
// chunk (p - row) & 3, so fragment reads spread across banks (8-way -> ~2-way).
__device__ __forceinline__ void store_out(float* p, float v) { *p = v; }
__device__ __forceinline__ void store_out(u16* p, float v) { *p = f2b(v); }

template <typename OutT>
__global__ __launch_bounds__(256) void gemm_bt(const u16* __restrict__ A,
                                               const u16* __restrict__ Bw,
                                               const float* __restrict__ rowscale,
                                               OutT* __restrict__ C,
                                               int M, int N, int K) {
  __shared__ __align__(16) u16 As[128 * 32];
  __shared__ __align__(16) u16 Bs[128 * 32];
  const int tid = threadIdx.x;
  const int lane = tid & 63;
  const int wv = tid >> 6;
  const int wm = wv >> 1, wn = wv & 1;
  const int m0 = blockIdx.y * 128, n0 = blockIdx.x * 128;
  const int g = lane >> 4, c15 = lane & 15;
  f32x4 acc[4][4] = {};

  const int c0 = 2 * wv, c1 = c0 + 1;         // this wave's staging chunks
  const int srow = lane >> 2;                 // 0..15 row within chunk
  const int pch = lane & 3;                   // physical 16B chunk slot
  const int scol = (((pch - srow) & 3)) * 8;  // logical chunk -> global col
  const u16* Ag0 = A + (size_t)(m0 + c0 * 16 + srow) * K + scol;
  const u16* Ag1 = A + (size_t)(m0 + c1 * 16 + srow) * K + scol;
  const u16* Bg0 = Bw + (size_t)(n0 + c0 * 16 + srow) * K + scol;
  const u16* Bg1 = Bw + (size_t)(n0 + c1 * 16 + srow) * K + scol;
  u16* Al0 = As + c0 * 512 + lane * 8;
  u16* Al1 = As + c1 * 512 + lane * 8;
  u16* Bl0 = Bs + c0 * 512 + lane * 8;
  u16* Bl1 = Bs + c1 * 512 + lane * 8;

  for (int kb = 0; kb < K; kb += 32) {
    __syncthreads();
    async16(Ag0 + kb, Al0);
    async16(Ag1 + kb, Al1);
    async16(Bg0 + kb, Bl0);
    async16(Bg1 + kb, Bl1);
    __syncthreads();
    bf16x8 af[4], bf[4];
#pragma unroll
    for (int i = 0; i < 4; i++) {
      af[i] = ld8(As + (wm * 64 + i * 16 + c15) * 32 + ((g + c15) & 3) * 8);
      bf[i] = ld8(Bs + (wn * 64 + i * 16 + c15) * 32 + ((g + c15) & 3) * 8);
    }
#pragma unroll
    for (int i = 0; i < 4; i++)
#pragma unroll
      for (int j = 0; j < 4; j++) acc[i][j] = mfma16x16(af[i], bf[j], acc[i][j]);
  }
#pragma unroll
  for (int i = 0; i < 4; i++) {
#pragma unroll
    for (int r = 0; r < 4; r++) {
      int m = m0 + wm * 64 + i * 16 + g * 4 + r;
      float sc = rowscale[m];
#pragma unroll
      for (int j = 0; j < 4; j++) {
        int n = n0 + wn * 64 + j * 16 + c15;
        store_out(C + (size_t)m * N + n, acc[i][j][r] * sc);
      }
    }
  }
}

// ---------------- flash attention (causal, GQA 4:1) ----------------
// Barrier-free: each wave owns a 32-row q-tile and loads K/V fragments
// directly from global (L2-resident). P transform round-trips wave-private
// LDS. Row-sum l via ones-MFMA (acc[8]).
//
// Load balance: wave handles the q-tile PAIR (a, 63-a) sequentially; step
// count = (a/2+1)+((63-a)/2+1) = 33 for EVERY a, so all 2048 waves are
// identical and per-SIMD balance holds under any scheduler/XCD mapping.
// Full (off-diagonal) steps take a mask-free fast path.

struct AttnState {
  f32x4 acc[2][9];
  float mrun[2][4];
};

template <bool FULL>
__device__ __forceinline__ void attn_step(
    int j0, int q0, const u16* kbase, const u16* vbase, u16* pw0, u16* pw1,
    const bf16x8 qf[2][4], AttnState& st, int g, int c15, const bf16x8 vones) {
  const int qmax = q0 + 31;
  f32x4 sc[2][4];
#pragma unroll
  for (int nt = 0; nt < 4; nt++) {
    if (FULL || (j0 + nt * 16 <= qmax)) {
      bf16x8 kf[4];
      const u16* kp = kbase + (size_t)(j0 + nt * 16) * 6144;
#pragma unroll
      for (int c = 0; c < 4; c++) kf[c] = ld8(kp + c * 32);
      f32x4 s0 = {0.f, 0.f, 0.f, 0.f}, s1 = {0.f, 0.f, 0.f, 0.f};
#pragma unroll
      for (int c = 0; c < 4; c++) {
        s0 = mfma16x16(qf[0][c], kf[c], s0);
        s1 = mfma16x16(qf[1][c], kf[c], s1);
      }
      if (FULL) {
#pragma unroll
        for (int r = 0; r < 4; r++) {
          sc[0][nt][r] = s0[r] * 0.08838834764831845f;
          sc[1][nt][r] = s1[r] * 0.08838834764831845f;
        }
      } else {
        const int key = j0 + nt * 16 + c15;
#pragma unroll
        for (int r = 0; r < 4; r++) {
          sc[0][nt][r] =
              (key <= q0 + g * 4 + r) ? s0[r] * 0.08838834764831845f : -INFINITY;
          sc[1][nt][r] =
              (key <= q0 + 16 + g * 4 + r) ? s1[r] * 0.08838834764831845f : -INFINITY;
        }
      }
    }
  }
  // online softmax per m-tile
#pragma unroll
  for (int m = 0; m < 2; m++) {
    u16* pw = m ? pw1 : pw0;
    float alpha[4];
#pragma unroll
    for (int r = 0; r < 4; r++) {
      float rm = -INFINITY;
#pragma unroll
      for (int nt = 0; nt < 4; nt++)
        if (FULL || (j0 + nt * 16 <= qmax)) rm = fmaxf(rm, sc[m][nt][r]);
      rm = fmaxf(rm, __shfl_xor(rm, 1));
      rm = fmaxf(rm, __shfl_xor(rm, 2));
      rm = fmaxf(rm, __shfl_xor(rm, 4));
      rm = fmaxf(rm, __shfl_xor(rm, 8));
      float mnew = fmaxf(st.mrun[m][r], rm);
      alpha[r] = __expf(st.mrun[m][r] - mnew);
      st.mrun[m][r] = mnew;
#pragma unroll
      for (int nt = 0; nt < 4; nt++) {
        float pv = (FULL || (j0 + nt * 16 <= qmax))
                       ? __expf(sc[m][nt][r] - mnew) : 0.0f;
        pw[(g * 4 + r) * 72 + nt * 16 + c15] = f2b(pv);
      }
    }
#pragma unroll
    for (int dt = 0; dt < 9; dt++)
#pragma unroll
      for (int r = 0; r < 4; r++) st.acc[m][dt][r] *= alpha[r];
  }
  // PV: V fragments straight from global; ones-column accumulates l
#pragma unroll
  for (int kc = 0; kc < 2; kc++) {
    bf16x8 pf0 = ld8(pw0 + c15 * 72 + kc * 32 + g * 8);
    bf16x8 pf1 = ld8(pw1 + c15 * 72 + kc * 32 + g * 8);
#pragma unroll
    for (int dt = 0; dt < 8; dt++) {
      bf16x8 vf = ld8(vbase + (size_t)(dt * 16) * 2048 + j0 + kc * 32);
      st.acc[0][dt] = mfma16x16(pf0, vf, st.acc[0][dt]);
      st.acc[1][dt] = mfma16x16(pf1, vf, st.acc[1][dt]);
    }
    st.acc[0][8] = mfma16x16(pf0, vones, st.acc[0][8]);
    st.acc[1][8] = mfma16x16(pf1, vones, st.acc[1][8]);
  }
}

// grid (8, 32, 2), block 256. Wave wv handles pair a = blockIdx.x*4+wv.
__global__ __launch_bounds__(256, 2) void attn_kernel(const u16* __restrict__ qkvb,
                                                      const u16* __restrict__ vtb,
                                                      float* __restrict__ out) {
  __shared__ __align__(16) u16 Ps[4][2][16 * 72];   // per-wave, per-m-tile P
  const int tid = threadIdx.x, lane = tid & 63, wv = tid >> 6;
  const int g = lane >> 4, c15 = lane & 15;
  const int a = blockIdx.x * 4 + wv;                // 0..31
  const int h = blockIdx.y, b = blockIdx.z, kvh = h >> 2;
  const bf16x8 vones = ones8();
  const u16* kbase =
      qkvb + (size_t)(b * 2048 + c15) * 6144 + 4096 + kvh * 128 + g * 8;
  const u16* vbase = vtb + (size_t)((b * 8 + kvh) * 128 + c15) * 2048 + g * 8;
  u16* pw0 = &Ps[wv][0][0];
  u16* pw1 = &Ps[wv][1][0];

  for (int half = 0; half < 2; half++) {
    const int qt = half ? (63 - a) : a;
    const int q0 = qt * 32;
    bf16x8 qf[2][4];
#pragma unroll
    for (int m = 0; m < 2; m++) {
      const u16* qp =
          qkvb + (size_t)(b * 2048 + q0 + m * 16 + c15) * 6144 + h * 128 + g * 8;
#pragma unroll
      for (int c = 0; c < 4; c++) qf[m][c] = ld8(qp + c * 32);
    }
    AttnState st;
#pragma unroll
    for (int m = 0; m < 2; m++)
#pragma unroll
      for (int dt = 0; dt < 9; dt++) st.acc[m][dt] = f32x4{0.f, 0.f, 0.f, 0.f};
#pragma unroll
    for (int m = 0; m < 2; m++)
#pragma unroll
      for (int r = 0; r < 4; r++) st.mrun[m][r] = -INFINITY;

    const int nfull = qt >> 1;                 // full 64-key steps
    for (int jt = 0; jt < nfull; jt++)
      attn_step<true>(jt * 64, q0, kbase, vbase, pw0, pw1, qf, st, g, c15, vones);
    attn_step<false>(nfull * 64, q0, kbase, vbase, pw0, pw1, qf, st, g, c15, vones);

    // epilogue: normalize by l (= acc[8]) and store fp32
#pragma unroll
    for (int m = 0; m < 2; m++)
#pragma unroll
      for (int r = 0; r < 4; r++) {
        const int row = q0 + m * 16 + g * 4 + r;
        float inv = 1.0f / st.acc[m][8][r];
        float* op = out + (size_t)(b * 2048 + row) * 4096 + h * 128;
#pragma unroll
        for (int dt = 0; dt < 8; dt++) op[dt * 16 + c15] = st.acc[m][dt][r] * inv;
      }
  }
}

// ---------------- per-row quantization ----------------
__global__ __launch_bounds__(256) void quant_kernel(const float* __restrict__ attn,
                                                    u16* __restrict__ aq,
                                                    float* __restrict__ ascale) {
  const int t = blockIdx.x, tid = threadIdx.x;
  const float* row = attn + (size_t)t * 4096;
  float vals[16];
  float am = 0.f;
#pragma unroll
  for (int i = 0; i < 16; i++) {
    float v = row[tid + i * 256];
    vals[i] = v;
    am = fmaxf(am, fabsf(v));
  }
#pragma unroll
  for (int m = 1; m <= 32; m <<= 1) am = fmaxf(am, __shfl_xor(am, m));
  __shared__ float red[4];
  if ((tid & 63) == 0) red[tid >> 6] = am;
  __syncthreads();
  am = fmaxf(fmaxf(red[0], red[1]), fmaxf(red[2], red[3]));
  float asc = fmaxf(am, 1e-6f) / 127.0f;
  if (tid == 0) ascale[t] = asc;
#pragma unroll
  for (int i = 0; i < 16; i++) {
    float q = rintf(vals[i] / asc);
    q = fminf(127.0f, fmaxf(-127.0f, q));
    aq[(size_t)t * 4096 + tid + i * 256] = f2b(q);  // small ints exact in bf16
  }
}

// ---------------- launch ----------------
extern "C" void kernel_launch(void* const* d_in, const int* in_sizes, int n_in,
                              void* d_out, int out_size, void* d_ws, size_t ws_size,
                              hipStream_t stream) {
  const int* q_hidden = (const int*)d_in[0];
  const float* q_scale = (const float*)d_in[1];
  const int* w_qkv = (const int*)d_in[3];
  const float* s_qkv = (const float*)d_in[4];
  const int* w_o = (const int*)d_in[5];
  const float* s_o = (const float*)d_in[6];
  float* out = (float*)d_out;

  char* ws = (char*)d_ws;
  const size_t MB = 1024 * 1024;
  // ws layout (96 MB peak, regions reused across phases):
  u16* WB = (u16*)(ws);                // [0,48MB) wqkv bf16 (dead after gemm1)
  u16* QKVB = (u16*)(ws + 48 * MB);    // [48,96MB) qkv bf16 (dead after attention)
  u16* VTB = (u16*)(ws);               // [0,8MB) V^T (after gemm1)
  u16* ATTNQ = (u16*)(ws + 8 * MB);    // [8,40MB) attn_q bf16
  float* ASC = (float*)(ws + 40 * MB); // [40MB,+16KB) per-row scales
  u16* WOB = (u16*)(ws + 48 * MB);     // [48,80MB) w_o bf16 (after attention)
  u16* XB = (u16*)d_out;               // x bf16 in d_out (dead after gemm1)

  convert_x<<<16384, 256, 0, stream>>>(q_hidden, XB);
  dequant_w<<<24576, 256, 0, stream>>>(w_qkv, s_qkv, WB);
  gemm_bt<u16><<<dim3(48, 32), 256, 0, stream>>>(XB, WB, q_scale, QKVB,
                                                 T_, OQKV_, HID_);
  rope_kernel<<<40960, 256, 0, stream>>>(QKVB);
  vt_transpose<<<dim3(32, 2, 16), 256, 0, stream>>>(QKVB, VTB);
  attn_kernel<<<dim3(8, 32, 2), 256, 0, stream>>>(QKVB, VTB, out);
  quant_kernel<<<4096, 256, 0, stream>>>(out, ATTNQ, ASC);
  dequant_w<<<16384, 256, 0, stream>>>(w_o, s_o, WOB);
  gemm_bt<float><<<dim3(32, 32), 256, 0, stream>>>(ATTNQ, WOB, ASC, out,
                                                   T_, HID_, HID_);
}